// Round 3
// baseline (1649.044 us; speedup 1.0000x reference)
//
#include <hip/hip_runtime.h>
#include <cstddef>
#include <cmath>

// Problem constants
#define B_    64
#define L_    128
#define V_    20000
#define D_    300
#define H_    256
#define NE_   34
#define NA_   36
#define M_    8192      // L_*B_
#define KP_   304       // D_ padded to multiple of 16
#define NPROJ_ 2048     // 2 dirs * 4H
#define K2_   512       // 2H
#define NCAT_ 128       // 36 (part_j) + 36 (part_i) + 34 (logit_h) padded to 128

__device__ __forceinline__ float sigmoidf_(float x) { return 1.0f / (1.0f + expf(-x)); }

typedef __attribute__((ext_vector_type(2))) _Float16 half2_;

__device__ __forceinline__ half2_ u2h(unsigned u) {
    union { unsigned u; half2_ h; } c; c.u = u; return c.h;
}
__device__ __forceinline__ unsigned packh2(float a, float b) {
    union { half2_ h; unsigned u; } c;
    c.h = half2_{(_Float16)a, (_Float16)b};
    return c.u;
}

#if __has_builtin(__builtin_amdgcn_fdot2)
__device__ __forceinline__ float fdot2_(half2_ a, half2_ b, float c) {
    return __builtin_amdgcn_fdot2(a, b, c, false);
}
#else
__device__ __forceinline__ float fdot2_(half2_ a, half2_ b, float c) {
    return c + (float)a.x * (float)b.x + (float)a.y * (float)b.y;
}
#endif

// ---------------------------------------------------------------------------
// K1: gather embeddings into X (M_ x KP_), zero-padded K tail. X[m][k], m = l*B_+b
__global__ __launch_bounds__(256) void k_gather(const float* __restrict__ emb,
                                                const int* __restrict__ ids,
                                                float* __restrict__ X) {
    int idx = blockIdx.x * 256 + threadIdx.x;
    if (idx >= M_ * KP_) return;
    int m = idx / KP_, k = idx - m * KP_;
    int l = m >> 6, b = m & 63;
    float v = 0.f;
    if (k < D_) {
        int tok = ids[b * L_ + l];
        v = emb[(size_t)tok * D_ + k];
    }
    X[idx] = v;
}

// K2: transposed input-proj weights Wt_ih (KP_ x NPROJ_) + combined bias
__global__ __launch_bounds__(256) void k_prep_wih(const float* __restrict__ Wf,
                                                  const float* __restrict__ Wb,
                                                  const float* __restrict__ bihf,
                                                  const float* __restrict__ bhhf,
                                                  const float* __restrict__ bihb,
                                                  const float* __restrict__ bhhb,
                                                  float* __restrict__ Wt,
                                                  float* __restrict__ bias) {
    int idx = blockIdx.x * 256 + threadIdx.x;
    if (idx >= KP_ * NPROJ_) return;
    int k = idx / NPROJ_, n = idx - k * NPROJ_;
    int dir = n >> 10, g = n & 1023;
    float v = 0.f;
    if (k < D_) v = dir ? Wb[g * D_ + k] : Wf[g * D_ + k];
    Wt[idx] = v;
    if (k == 0) bias[n] = dir ? (bihb[g] + bhhb[g]) : (bihf[g] + bhhf[g]);
}

// K3: pack W_hh to fp16 half2, k-major: Wp[dir][kp][g] = (W[g][2kp], W[g][2kp+1])
// Also zeroes the inter-block sync flags for k_lstm5 (flg lives in a
// never-otherwise-written workspace gap, so ordering is a non-issue).
__global__ __launch_bounds__(256) void k_prep_whh16(const float* __restrict__ Wf,
                                                    const float* __restrict__ Wb,
                                                    unsigned* __restrict__ Wp,
                                                    unsigned* __restrict__ flg) {
    int idx = blockIdx.x * 256 + threadIdx.x;       // 2*128*1024
    if (idx < 64) flg[idx] = 0u;
    if (idx >= 2 * 128 * 1024) return;
    int dir = idx >> 17, r = idx & 131071;
    int kp = r >> 10, g = r & 1023;
    const float* W = dir ? Wb : Wf;
    Wp[idx] = packh2(W[g * H_ + 2 * kp], W[g * H_ + 2 * kp + 1]);
}

// K4: combined head weights Wcat (K2_ x NCAT_)
__global__ __launch_bounds__(256) void k_prep_wcat(const float* __restrict__ Warg,
                                                   const float* __restrict__ Wev,
                                                   const float* __restrict__ barg,
                                                   const float* __restrict__ bev,
                                                   float* __restrict__ Wcat,
                                                   float* __restrict__ bias) {
    int idx = blockIdx.x * 256 + threadIdx.x;
    if (idx >= K2_ * NCAT_) return;
    int k = idx >> 7, n = idx & 127;
    float v = 0.f;
    if (n < 36)       v = Warg[n * 1024 + k];
    else if (n < 72)  v = Warg[(n - 36) * 1024 + 512 + k];
    else if (n < 106) v = Wev[(n - 72) * 545 + k];
    Wcat[idx] = v;
    if (k == 0) {
        float bv = 0.f;
        if (n >= 36 && n < 72)       bv = barg[n - 36];
        else if (n >= 72 && n < 106) bv = bev[n - 72];
        bias[n] = bv;
    }
}

// ---------------------------------------------------------------------------
// Generic fp32 tiled GEMM: C (MxN) = A (MxK) * Bm (KxN) + bias[n]
template <int K>
__global__ __launch_bounds__(256) void k_gemm(const float* __restrict__ A,
                                              const float* __restrict__ Bm,
                                              const float* __restrict__ bias,
                                              float* __restrict__ C, int N) {
    __shared__ float As[16][64];
    __shared__ float Bs[16][64];
    const int tid = threadIdx.x;
    const int m0 = blockIdx.x * 64, n0 = blockIdx.y * 64;
    const int tx = tid & 15, ty = tid >> 4;
    const int a_m = tid >> 2;
    const int a_k = (tid & 3) << 2;
    const int b_k = tid >> 4;
    const int b_n = (tid & 15) << 2;

    float acc[4][4] = {};
    for (int k0 = 0; k0 < K; k0 += 16) {
        float4 av = *(const float4*)&A[(size_t)(m0 + a_m) * K + k0 + a_k];
        float4 bv = *(const float4*)&Bm[(size_t)(k0 + b_k) * N + n0 + b_n];
        __syncthreads();
        As[a_k][a_m] = av.x; As[a_k + 1][a_m] = av.y;
        As[a_k + 2][a_m] = av.z; As[a_k + 3][a_m] = av.w;
        *(float4*)&Bs[b_k][b_n] = bv;
        __syncthreads();
#pragma unroll
        for (int kk = 0; kk < 16; kk++) {
            float4 a4 = *(const float4*)&As[kk][ty << 2];
            float4 b4 = *(const float4*)&Bs[kk][tx << 2];
            float ar[4] = {a4.x, a4.y, a4.z, a4.w};
            float br[4] = {b4.x, b4.y, b4.z, b4.w};
#pragma unroll
            for (int i = 0; i < 4; i++)
#pragma unroll
                for (int j = 0; j < 4; j++) acc[i][j] += ar[i] * br[j];
        }
    }
    float4 bb = *(const float4*)&bias[n0 + (tx << 2)];
#pragma unroll
    for (int i = 0; i < 4; i++) {
        int m = m0 + (ty << 2) + i;
        float4 o;
        o.x = acc[i][0] + bb.x; o.y = acc[i][1] + bb.y;
        o.z = acc[i][2] + bb.z; o.w = acc[i][3] + bb.w;
        *(float4*)&C[(size_t)m * N + n0 + (tx << 2)] = o;
    }
}

// ---------------------------------------------------------------------------
// BiLSTM v5b: LDS-resident weights (identical compute to v5; only the
// hx/flg workspace placement changed — v5 accidentally placed flg inside
// the live X region, corrupting 64 embedding values read by gemm1).
//   grid = 256 blocks = q(4) x dir(2) x bg(32), exactly 1 block/CU (149 KB LDS).
//   block = 512 threads: ks = tid>>6 (kp-slice of 16 kp-pairs), t = tid&63.
//   Each block keeps its 128 KB W-slice in LDS for all 128 steps; the 4
//   sibling blocks of a (dir, batch-pair) exchange fp16-packed h through a
//   double-buffered global staging area with agent-scope release/acquire
//   flag sync each step.
__global__ __launch_bounds__(512, 1) void k_lstm5(const float* __restrict__ pre,
                                                  const unsigned* __restrict__ Wp,
                                                  float* __restrict__ hs,
                                                  unsigned* __restrict__ hx,
                                                  unsigned* __restrict__ flg) {
    extern __shared__ __align__(16) char smem[];
    unsigned* Wl   = (unsigned*)smem;                // [128 kp][256 gl]  = 131072 B
    float*    pbuf = (float*)(smem + 131072);        // [8 ks][2 r][256]  =  16384 B
    unsigned* h2s  = (unsigned*)(smem + 147456);     // [2 r][128 kp]     =   1024 B

    const int blk = blockIdx.x;
    const int q   = blk >> 6;                        // unit-slice 0..3
    const int dir = (blk >> 5) & 1;
    const int bg  = blk & 31;                        // batch pair group
    const int b0  = bg << 1;
    const int tid = threadIdx.x;
    const int ks  = tid >> 6;                        // kp-slice 0..7
    const int t   = tid & 63;

    // ---- prologue: load W slice into LDS, zero h-state ----
    const unsigned* Wd = Wp + ((size_t)dir << 17);
    for (int i = 0; i < 16; ++i) {
        int i2 = tid + (i << 9);                     // 0..8191 uint4s
        int kp = i2 >> 6;
        int c  = i2 & 63;
        int ty = c >> 4, u4 = c & 15;
        uint4 w = *(const uint4*)(Wd + (kp << 10) + (ty << 8) + (q << 6) + (u4 << 2));
        *(uint4*)&Wl[(kp << 8) + (ty << 6) + (u4 << 2)] = w;
    }
    if (tid < 256) h2s[tid] = 0u;
    __syncthreads();

    unsigned* myflag = flg + (dir << 5) + bg;
    float c_state = 0.f;                             // live for tid < 128

    const int ksl = ks << 4;                         // kp base of this slice
    const unsigned* wrow = &Wl[(ksl << 8) + (t << 2)];

    for (int step = 0; step < L_; ++step) {
        const int l = dir ? (L_ - 1 - step) : step;

        // ---- dot phase: all 8 waves ----
        float4 a0, a1;
        if (ks == 0) {
            const float* p0 = pre + ((size_t)(l * B_ + b0) << 11) + (dir << 10)
                              + ((t >> 4) << 8) + (q << 6) + ((t & 15) << 2);
            a0 = *(const float4*)p0;
            a1 = *(const float4*)(p0 + NPROJ_);
        } else {
            a0 = make_float4(0.f, 0.f, 0.f, 0.f);
            a1 = make_float4(0.f, 0.f, 0.f, 0.f);
        }
        // h2 slice (wave-uniform broadcast reads)
        uint4 hA0 = *(const uint4*)&h2s[ksl];
        uint4 hB0 = *(const uint4*)&h2s[ksl + 4];
        uint4 hC0 = *(const uint4*)&h2s[ksl + 8];
        uint4 hD0 = *(const uint4*)&h2s[ksl + 12];
        uint4 hA1 = *(const uint4*)&h2s[128 + ksl];
        uint4 hB1 = *(const uint4*)&h2s[128 + ksl + 4];
        uint4 hC1 = *(const uint4*)&h2s[128 + ksl + 8];
        uint4 hD1 = *(const uint4*)&h2s[128 + ksl + 12];
        unsigned hu0[16] = {hA0.x, hA0.y, hA0.z, hA0.w, hB0.x, hB0.y, hB0.z, hB0.w,
                            hC0.x, hC0.y, hC0.z, hC0.w, hD0.x, hD0.y, hD0.z, hD0.w};
        unsigned hu1[16] = {hA1.x, hA1.y, hA1.z, hA1.w, hB1.x, hB1.y, hB1.z, hB1.w,
                            hC1.x, hC1.y, hC1.z, hC1.w, hD1.x, hD1.y, hD1.z, hD1.w};
#pragma unroll
        for (int j = 0; j < 16; ++j) {
            uint4 w = *(const uint4*)(wrow + (j << 8));
            half2_ h0 = u2h(hu0[j]);
            half2_ h1 = u2h(hu1[j]);
            a0.x = fdot2_(u2h(w.x), h0, a0.x);
            a0.y = fdot2_(u2h(w.y), h0, a0.y);
            a0.z = fdot2_(u2h(w.z), h0, a0.z);
            a0.w = fdot2_(u2h(w.w), h0, a0.w);
            a1.x = fdot2_(u2h(w.x), h1, a1.x);
            a1.y = fdot2_(u2h(w.y), h1, a1.y);
            a1.z = fdot2_(u2h(w.z), h1, a1.z);
            a1.w = fdot2_(u2h(w.w), h1, a1.w);
        }
        *(float4*)&pbuf[((ks << 1) + 0) * 256 + (t << 2)] = a0;
        *(float4*)&pbuf[((ks << 1) + 1) * 256 + (t << 2)] = a1;
        __syncthreads();                             // B1: partials ready

        // ---- cell update: 2 waves (r = row, ul = local unit) ----
        const int par = step & 1;
        unsigned* hxq = hx + ((((par << 1) + dir) << 5) + bg) * 256;
        if (tid < 128) {
            const int r = tid >> 6, ul = tid & 63;
            float s0 = 0.f, s1 = 0.f, s2 = 0.f, s3 = 0.f;
#pragma unroll
            for (int k = 0; k < 8; ++k) {
                const float* pb = &pbuf[(((k << 1) + r) << 8)];
                s0 += pb[ul];
                s1 += pb[64 + ul];
                s2 += pb[128 + ul];
                s3 += pb[192 + ul];
            }
            float ig = sigmoidf_(s0);
            float fg = sigmoidf_(s1);
            float gg = tanhf(s2);
            float og = sigmoidf_(s3);
            float c = fg * c_state + ig * gg;
            c_state = c;
            float h = og * tanhf(c);
            hs[((size_t)(l * B_ + b0 + r) << 9) + (dir << 8) + (q << 6) + ul] = h;
            float hn = __shfl_xor(h, 1, 64);
            if (!(ul & 1) && step < L_ - 1) {
                hxq[(r << 7) + (q << 5) + (ul >> 1)] = packh2(h, hn);
            }
        }
        if (step == L_ - 1) break;                   // uniform: no exchange after last step

        __syncthreads();                             // B2: hx stores drained (vmcnt0 before barrier)
        if (tid == 0) {
            __hip_atomic_fetch_add(myflag, 1u, __ATOMIC_RELEASE, __HIP_MEMORY_SCOPE_AGENT);
            const unsigned tgt = 4u * (unsigned)(step + 1);
            int guard = 0;
            while (__hip_atomic_load(myflag, __ATOMIC_RELAXED, __HIP_MEMORY_SCOPE_AGENT) < tgt) {
                __builtin_amdgcn_s_sleep(1);
                if (++guard > (1 << 26)) break;      // turn a residency pathology into fast-fail
            }
            __builtin_amdgcn_fence(__ATOMIC_ACQUIRE, "agent");
        }
        __syncthreads();                             // B3: all siblings' h visible
        if (tid < 256) h2s[tid] = hxq[tid];
        __syncthreads();                             // B4: h2s ready for next step
    }
}

// ---------------------------------------------------------------------------
// Event head sequential scan. One block (1 wave) per batch row.
__global__ __launch_bounds__(64) void k_event(const float* __restrict__ part,
                                              const float* __restrict__ Wev,
                                              float* __restrict__ out_ev) {
    const int b = blockIdx.x;
    const int e = threadIdx.x;
    __shared__ float sg[33];
    if (e < 33) sg[e] = 0.f;
    float wreg[33];
    if (e < NE_) {
#pragma unroll
        for (int j = 0; j < 33; j++) wreg[j] = Wev[e * 545 + 512 + j];
    }
    __syncthreads();
    for (int l = 0; l < L_; l++) {
        const int m = l * B_ + b;
        float v = -3.0e38f;
        if (e < NE_) {
            v = part[(size_t)m * NCAT_ + 72 + e];
#pragma unroll
            for (int j = 0; j < 33; j++) v += wreg[j] * sg[j];
            out_ev[((size_t)b * L_ + l) * NE_ + e] = v;
        }
        float bv = v;
        int bi = e;
#pragma unroll
        for (int off = 32; off > 0; off >>= 1) {
            float ov = __shfl_xor(bv, off, 64);
            int oi = __shfl_xor(bi, off, 64);
            if (ov > bv || (ov == bv && oi < bi)) { bv = ov; bi = oi; }
        }
        __syncthreads();
        if (bi > 0 && e == bi - 1) sg[e] = 1.f;
        __syncthreads();
    }
}

// ---------------------------------------------------------------------------
// Argument logits broadcast: out[b][i][j][a] = part_i[b][i][a] + part_j[b][j][a]
__global__ __launch_bounds__(256) void k_arg(const float* __restrict__ part,
                                             float* __restrict__ out) {
    const int blk = blockIdx.x;            // b*L_ + i
    const int b = blk >> 7, i = blk & 127;
    __shared__ float pj[L_ * NA_];
    __shared__ float pi_s[NA_];
    const int tid = threadIdx.x;
    if (tid < NA_) pi_s[tid] = part[(size_t)(i * B_ + b) * NCAT_ + 36 + tid];
    for (int idx = tid; idx < L_ * NA_; idx += 256) {
        int j = idx / NA_, a = idx - j * NA_;
        pj[idx] = part[(size_t)(j * B_ + b) * NCAT_ + a];
    }
    __syncthreads();
    float* o = out + (size_t)blk * (L_ * NA_);
    for (int idx = tid; idx < L_ * NA_; idx += 256) {
        int a = idx % NA_;
        o[idx] = pi_s[a] + pj[idx];
    }
}

// ---------------------------------------------------------------------------
extern "C" void kernel_launch(void* const* d_in, const int* in_sizes, int n_in,
                              void* d_out, int out_size, void* d_ws, size_t ws_size,
                              hipStream_t stream) {
    const float* emb  = (const float*)d_in[0];
    const float* Wihf = (const float*)d_in[1];
    const float* Whhf = (const float*)d_in[2];
    const float* bihf = (const float*)d_in[3];
    const float* bhhf = (const float*)d_in[4];
    const float* Wihb = (const float*)d_in[5];
    const float* Whhb = (const float*)d_in[6];
    const float* bihb = (const float*)d_in[7];
    const float* bhhb = (const float*)d_in[8];
    const float* Wev  = (const float*)d_in[9];
    const float* bev  = (const float*)d_in[10];
    const float* Warg = (const float*)d_in[11];
    const float* barg = (const float*)d_in[12];
    const int*   ids  = (const int*)d_in[13];
    float* out = (float*)d_out;
    float* ws  = (float*)d_ws;

    // Workspace layout (floats). X region reused for `part` (post-lstm only).
    // flg/hx live in the permanently-unused gap [3377152, 3639296) between
    // Wp16's end and Wcat — written by no other kernel (v5's bug was placing
    // them inside live X).
    float*    X       = ws;                 // 8192*304  (dead after gemm1)
    float*    part    = ws;                 // 8192*128 (written by gemm2, after lstm)
    float*    Wt_ih   = ws + 2490368;       // 304*2048
    float*    bias_p  = ws + 3112960;       // 2048
    unsigned* Wp16    = (unsigned*)(ws + 3115008);  // 2*128*1024 uints (262144)
    unsigned* flg     = (unsigned*)(ws + 3377152);  // 64 counters (in gap)
    unsigned* hx      = (unsigned*)(ws + 3377216);  // 32768 uints: [par][dir][bg][r][128] (in gap)
    float*    Wcat    = ws + 3639296;       // 512*128
    float*    bias_c  = ws + 3704832;       // 128
    float*    pre_all = ws + 3704960;       // 8192*2048
    float*    hsbuf   = ws + 20482176;      // 8192*512

    static bool s_attr_done = false;
    if (!s_attr_done) {
        (void)hipFuncSetAttribute(reinterpret_cast<const void*>(k_lstm5),
                                  hipFuncAttributeMaxDynamicSharedMemorySize, 148480);
        s_attr_done = true;
    }

    k_gather<<<(M_ * KP_) / 256, 256, 0, stream>>>(emb, ids, X);
    k_prep_wih<<<(KP_ * NPROJ_) / 256, 256, 0, stream>>>(Wihf, Wihb, bihf, bhhf, bihb, bhhb, Wt_ih, bias_p);
    k_prep_whh16<<<(2 * 128 * 1024) / 256, 256, 0, stream>>>(Whhf, Whhb, Wp16, flg);
    k_prep_wcat<<<(K2_ * NCAT_) / 256, 256, 0, stream>>>(Warg, Wev, barg, bev, Wcat, bias_c);

    k_gemm<KP_><<<dim3(M_ / 64, NPROJ_ / 64), 256, 0, stream>>>(X, Wt_ih, bias_p, pre_all, NPROJ_);
    k_lstm5<<<256, 512, 148480, stream>>>(pre_all, Wp16, hsbuf, hx, flg);
    k_gemm<K2_><<<dim3(M_ / 64, NCAT_ / 64), 256, 0, stream>>>(hsbuf, Wcat, bias_c, part, NCAT_);
    k_event<<<B_, 64, 0, stream>>>(part, Wev, out);
    k_arg<<<B_ * L_, 256, 0, stream>>>(part, out + (size_t)B_ * L_ * NE_);
}

// Round 4
// 970.960 us; speedup vs baseline: 1.6984x; 1.6984x over previous
//
#include <hip/hip_runtime.h>
#include <cstddef>
#include <cmath>

// Problem constants
#define B_    64
#define L_    128
#define V_    20000
#define D_    300
#define H_    256
#define NE_   34
#define NA_   36
#define M_    8192      // L_*B_
#define KP_   304       // D_ padded to multiple of 16
#define NPROJ_ 2048     // 2 dirs * 4H
#define K2_   512       // 2H
#define NCAT_ 128       // 36 (part_j) + 36 (part_i) + 34 (logit_h) padded to 128

__device__ __forceinline__ float sigmoidf_(float x) { return 1.0f / (1.0f + expf(-x)); }

typedef __attribute__((ext_vector_type(2))) _Float16 half2_;

__device__ __forceinline__ half2_ u2h(unsigned u) {
    union { unsigned u; half2_ h; } c; c.u = u; return c.h;
}
__device__ __forceinline__ unsigned packh2(float a, float b) {
    union { half2_ h; unsigned u; } c;
    c.h = half2_{(_Float16)a, (_Float16)b};
    return c.u;
}

#if __has_builtin(__builtin_amdgcn_fdot2)
__device__ __forceinline__ float fdot2_(half2_ a, half2_ b, float c) {
    return __builtin_amdgcn_fdot2(a, b, c, false);
}
#else
__device__ __forceinline__ float fdot2_(half2_ a, half2_ b, float c) {
    return c + (float)a.x * (float)b.x + (float)a.y * (float)b.y;
}
#endif

// ---------------------------------------------------------------------------
// K1: gather embeddings into X (M_ x KP_), zero-padded K tail. X[m][k], m = l*B_+b
__global__ __launch_bounds__(256) void k_gather(const float* __restrict__ emb,
                                                const int* __restrict__ ids,
                                                float* __restrict__ X) {
    int idx = blockIdx.x * 256 + threadIdx.x;
    if (idx >= M_ * KP_) return;
    int m = idx / KP_, k = idx - m * KP_;
    int l = m >> 6, b = m & 63;
    float v = 0.f;
    if (k < D_) {
        int tok = ids[b * L_ + l];
        v = emb[(size_t)tok * D_ + k];
    }
    X[idx] = v;
}

// K2: transposed input-proj weights Wt_ih (KP_ x NPROJ_) + combined bias
__global__ __launch_bounds__(256) void k_prep_wih(const float* __restrict__ Wf,
                                                  const float* __restrict__ Wb,
                                                  const float* __restrict__ bihf,
                                                  const float* __restrict__ bhhf,
                                                  const float* __restrict__ bihb,
                                                  const float* __restrict__ bhhb,
                                                  float* __restrict__ Wt,
                                                  float* __restrict__ bias) {
    int idx = blockIdx.x * 256 + threadIdx.x;
    if (idx >= KP_ * NPROJ_) return;
    int k = idx / NPROJ_, n = idx - k * NPROJ_;
    int dir = n >> 10, g = n & 1023;
    float v = 0.f;
    if (k < D_) v = dir ? Wb[g * D_ + k] : Wf[g * D_ + k];
    Wt[idx] = v;
    if (k == 0) bias[n] = dir ? (bihb[g] + bhhb[g]) : (bihf[g] + bhhf[g]);
}

// K3: pack W_hh to fp16 half2 in register-load order for k_lstm6:
//   uint4 element Wr4[(dir*32 + j)*1024 + g] = { w2(g, 4j+0..3) }
//   where w2(g, kp) = packh2(W[g][2kp], W[g][2kp+1]).
// Lane g of the lstm block reads chunk j at stride 16 B -> perfectly coalesced.
__global__ __launch_bounds__(256) void k_prep_whh16(const float* __restrict__ Wf,
                                                    const float* __restrict__ Wb,
                                                    unsigned* __restrict__ Wp) {
    int idx = blockIdx.x * 256 + threadIdx.x;       // 2*128*1024 uints
    if (idx >= 2 * 128 * 1024) return;
    int dir = idx >> 17, r = idx & 131071;
    int j = r >> 12;                                 // kp-chunk 0..31
    int g = (r >> 2) & 1023;                         // gate
    int c = r & 3;
    int kp = (j << 2) | c;
    const float* W = dir ? Wb : Wf;
    Wp[idx] = packh2(W[g * H_ + 2 * kp], W[g * H_ + 2 * kp + 1]);
}

// K4: combined head weights Wcat (K2_ x NCAT_)
__global__ __launch_bounds__(256) void k_prep_wcat(const float* __restrict__ Warg,
                                                   const float* __restrict__ Wev,
                                                   const float* __restrict__ barg,
                                                   const float* __restrict__ bev,
                                                   float* __restrict__ Wcat,
                                                   float* __restrict__ bias) {
    int idx = blockIdx.x * 256 + threadIdx.x;
    if (idx >= K2_ * NCAT_) return;
    int k = idx >> 7, n = idx & 127;
    float v = 0.f;
    if (n < 36)       v = Warg[n * 1024 + k];
    else if (n < 72)  v = Warg[(n - 36) * 1024 + 512 + k];
    else if (n < 106) v = Wev[(n - 72) * 545 + k];
    Wcat[idx] = v;
    if (k == 0) {
        float bv = 0.f;
        if (n >= 36 && n < 72)       bv = barg[n - 36];
        else if (n >= 72 && n < 106) bv = bev[n - 72];
        bias[n] = bv;
    }
}

// ---------------------------------------------------------------------------
// Generic fp32 tiled GEMM: C (MxN) = A (MxK) * Bm (KxN) + bias[n]
template <int K>
__global__ __launch_bounds__(256) void k_gemm(const float* __restrict__ A,
                                              const float* __restrict__ Bm,
                                              const float* __restrict__ bias,
                                              float* __restrict__ C, int N) {
    __shared__ float As[16][64];
    __shared__ float Bs[16][64];
    const int tid = threadIdx.x;
    const int m0 = blockIdx.x * 64, n0 = blockIdx.y * 64;
    const int tx = tid & 15, ty = tid >> 4;
    const int a_m = tid >> 2;
    const int a_k = (tid & 3) << 2;
    const int b_k = tid >> 4;
    const int b_n = (tid & 15) << 2;

    float acc[4][4] = {};
    for (int k0 = 0; k0 < K; k0 += 16) {
        float4 av = *(const float4*)&A[(size_t)(m0 + a_m) * K + k0 + a_k];
        float4 bv = *(const float4*)&Bm[(size_t)(k0 + b_k) * N + n0 + b_n];
        __syncthreads();
        As[a_k][a_m] = av.x; As[a_k + 1][a_m] = av.y;
        As[a_k + 2][a_m] = av.z; As[a_k + 3][a_m] = av.w;
        *(float4*)&Bs[b_k][b_n] = bv;
        __syncthreads();
#pragma unroll
        for (int kk = 0; kk < 16; kk++) {
            float4 a4 = *(const float4*)&As[kk][ty << 2];
            float4 b4 = *(const float4*)&Bs[kk][tx << 2];
            float ar[4] = {a4.x, a4.y, a4.z, a4.w};
            float br[4] = {b4.x, b4.y, b4.z, b4.w};
#pragma unroll
            for (int i = 0; i < 4; i++)
#pragma unroll
                for (int j = 0; j < 4; j++) acc[i][j] += ar[i] * br[j];
        }
    }
    float4 bb = *(const float4*)&bias[n0 + (tx << 2)];
#pragma unroll
    for (int i = 0; i < 4; i++) {
        int m = m0 + (ty << 2) + i;
        float4 o;
        o.x = acc[i][0] + bb.x; o.y = acc[i][1] + bb.y;
        o.z = acc[i][2] + bb.z; o.w = acc[i][3] + bb.w;
        *(float4*)&C[(size_t)m * N + n0 + (tx << 2)] = o;
    }
}

// ---------------------------------------------------------------------------
// BiLSTM v6: W_hh REGISTER-resident, one workgroup per recurrence chain.
//   Lessons: v3/v4 = L2 re-stream wall (~3.4 us/step); v5 = cross-block
//   per-step sync costs ~8.7 us/step. So: all state in ONE block, W in VGPRs.
//   grid = 128 blocks = dir(2) x batch row(64); block = 1024 threads = 16 waves.
//   Thread g owns gate g: its W row = 128 packed-fp16 uints = 32 uint4 in
//   registers (~128 VGPRs; 512 available at 4 waves/SIMD). Per step:
//   128 fdot2 against wave-uniform broadcast ds_read_b128 of the 512 B
//   h-state, LDS gate exchange, cell update on threads<256. 2 local barriers.
__global__ __launch_bounds__(1024) void k_lstm6(const float* __restrict__ pre,
                                                const unsigned* __restrict__ Wp,
                                                float* __restrict__ hs) {
    __shared__ float pbuf[1024];                  // gate exchange
    __shared__ __align__(16) unsigned h2s[128];   // h packed half2: h2s[i] = (h[2i], h[2i+1])

    const int blk = blockIdx.x;                   // dir*64 + b
    const int dir = blk >> 6;
    const int b   = blk & 63;
    const int g   = threadIdx.x;                  // gate 0..1023
    const int tid = threadIdx.x;

    // ---- prologue: W row into registers (coalesced uint4 loads) ----
    const uint4* Wr4 = (const uint4*)Wp;
    uint4 w[32];
#pragma unroll
    for (int j = 0; j < 32; ++j)
        w[j] = Wr4[(size_t)((dir << 5) + j) * 1024 + g];
    if (tid < 128) h2s[tid] = 0u;
    __syncthreads();

    const uint4* h2s4 = (const uint4*)h2s;
    float c_state = 0.f;                          // live for tid < 256 (unit u = tid)

    for (int step = 0; step < L_; ++step) {
        const int l = dir ? (L_ - 1 - step) : step;

        // ---- dot phase: all 16 waves, gate g ----
        float acc = pre[((size_t)(l * B_ + b) << 11) + (dir << 10) + g];
#pragma unroll
        for (int j = 0; j < 32; ++j) {
            uint4 h4 = h2s4[j];                   // wave-uniform broadcast read
            acc = fdot2_(u2h(w[j].x), u2h(h4.x), acc);
            acc = fdot2_(u2h(w[j].y), u2h(h4.y), acc);
            acc = fdot2_(u2h(w[j].z), u2h(h4.z), acc);
            acc = fdot2_(u2h(w[j].w), u2h(h4.w), acc);
        }
        pbuf[g] = acc;
        __syncthreads();                          // B1: gates ready

        // ---- cell update: threads 0..255 (unit u) ----
        if (tid < 256) {
            const int u = tid;
            float ig = sigmoidf_(pbuf[u]);
            float fg = sigmoidf_(pbuf[256 + u]);
            float gg = tanhf(pbuf[512 + u]);
            float og = sigmoidf_(pbuf[768 + u]);
            float c = fg * c_state + ig * gg;
            c_state = c;
            float h = og * tanhf(c);
            hs[((size_t)(l * B_ + b) << 9) + (dir << 8) + u] = h;
            float hn = __shfl_xor(h, 1, 64);      // partner u^1, same wave
            if (!(u & 1)) h2s[u >> 1] = packh2(h, hn);
        }
        __syncthreads();                          // B2: h2s ready for next step
    }
}

// ---------------------------------------------------------------------------
// Event head sequential scan. One block (1 wave) per batch row.
__global__ __launch_bounds__(64) void k_event(const float* __restrict__ part,
                                              const float* __restrict__ Wev,
                                              float* __restrict__ out_ev) {
    const int b = blockIdx.x;
    const int e = threadIdx.x;
    __shared__ float sg[33];
    if (e < 33) sg[e] = 0.f;
    float wreg[33];
    if (e < NE_) {
#pragma unroll
        for (int j = 0; j < 33; j++) wreg[j] = Wev[e * 545 + 512 + j];
    }
    __syncthreads();
    for (int l = 0; l < L_; l++) {
        const int m = l * B_ + b;
        float v = -3.0e38f;
        if (e < NE_) {
            v = part[(size_t)m * NCAT_ + 72 + e];
#pragma unroll
            for (int j = 0; j < 33; j++) v += wreg[j] * sg[j];
            out_ev[((size_t)b * L_ + l) * NE_ + e] = v;
        }
        float bv = v;
        int bi = e;
#pragma unroll
        for (int off = 32; off > 0; off >>= 1) {
            float ov = __shfl_xor(bv, off, 64);
            int oi = __shfl_xor(bi, off, 64);
            if (ov > bv || (ov == bv && oi < bi)) { bv = ov; bi = oi; }
        }
        __syncthreads();
        if (bi > 0 && e == bi - 1) sg[e] = 1.f;
        __syncthreads();
    }
}

// ---------------------------------------------------------------------------
// Argument logits broadcast: out[b][i][j][a] = part_i[b][i][a] + part_j[b][j][a]
__global__ __launch_bounds__(256) void k_arg(const float* __restrict__ part,
                                             float* __restrict__ out) {
    const int blk = blockIdx.x;            // b*L_ + i
    const int b = blk >> 7, i = blk & 127;
    __shared__ float pj[L_ * NA_];
    __shared__ float pi_s[NA_];
    const int tid = threadIdx.x;
    if (tid < NA_) pi_s[tid] = part[(size_t)(i * B_ + b) * NCAT_ + 36 + tid];
    for (int idx = tid; idx < L_ * NA_; idx += 256) {
        int j = idx / NA_, a = idx - j * NA_;
        pj[idx] = part[(size_t)(j * B_ + b) * NCAT_ + a];
    }
    __syncthreads();
    float* o = out + (size_t)blk * (L_ * NA_);
    for (int idx = tid; idx < L_ * NA_; idx += 256) {
        int a = idx % NA_;
        o[idx] = pi_s[a] + pj[idx];
    }
}

// ---------------------------------------------------------------------------
extern "C" void kernel_launch(void* const* d_in, const int* in_sizes, int n_in,
                              void* d_out, int out_size, void* d_ws, size_t ws_size,
                              hipStream_t stream) {
    const float* emb  = (const float*)d_in[0];
    const float* Wihf = (const float*)d_in[1];
    const float* Whhf = (const float*)d_in[2];
    const float* bihf = (const float*)d_in[3];
    const float* bhhf = (const float*)d_in[4];
    const float* Wihb = (const float*)d_in[5];
    const float* Whhb = (const float*)d_in[6];
    const float* bihb = (const float*)d_in[7];
    const float* bhhb = (const float*)d_in[8];
    const float* Wev  = (const float*)d_in[9];
    const float* bev  = (const float*)d_in[10];
    const float* Warg = (const float*)d_in[11];
    const float* barg = (const float*)d_in[12];
    const int*   ids  = (const int*)d_in[13];
    float* out = (float*)d_out;
    float* ws  = (float*)d_ws;

    // Workspace layout (floats). X region reused for `part` (post-lstm only).
    float*    X       = ws;                 // 8192*304  (dead after gemm1)
    float*    part    = ws;                 // 8192*128 (written by gemm2, after lstm)
    float*    Wt_ih   = ws + 2490368;       // 304*2048
    float*    bias_p  = ws + 3112960;       // 2048
    unsigned* Wp16    = (unsigned*)(ws + 3115008);  // 2*128*1024 uints (262144)
    float*    Wcat    = ws + 3639296;       // 512*128
    float*    bias_c  = ws + 3704832;       // 128
    float*    pre_all = ws + 3704960;       // 8192*2048
    float*    hsbuf   = ws + 20482176;      // 8192*512

    k_gather<<<(M_ * KP_) / 256, 256, 0, stream>>>(emb, ids, X);
    k_prep_wih<<<(KP_ * NPROJ_) / 256, 256, 0, stream>>>(Wihf, Wihb, bihf, bhhf, bihb, bhhb, Wt_ih, bias_p);
    k_prep_whh16<<<(2 * 128 * 1024) / 256, 256, 0, stream>>>(Whhf, Whhb, Wp16);
    k_prep_wcat<<<(K2_ * NCAT_) / 256, 256, 0, stream>>>(Warg, Wev, barg, bev, Wcat, bias_c);

    k_gemm<KP_><<<dim3(M_ / 64, NPROJ_ / 64), 256, 0, stream>>>(X, Wt_ih, bias_p, pre_all, NPROJ_);
    k_lstm6<<<128, 1024, 0, stream>>>(pre_all, Wp16, hsbuf);
    k_gemm<K2_><<<dim3(M_ / 64, NCAT_ / 64), 256, 0, stream>>>(hsbuf, Wcat, bias_c, part, NCAT_);
    k_event<<<B_, 64, 0, stream>>>(part, Wev, out);
    k_arg<<<B_ * L_, 256, 0, stream>>>(part, out + (size_t)B_ * L_ * NE_);
}

// Round 5
// 796.370 us; speedup vs baseline: 2.0707x; 1.2192x over previous
//
#include <hip/hip_runtime.h>
#include <cstddef>
#include <cmath>

// Problem constants
#define B_    64
#define L_    128
#define V_    20000
#define D_    300
#define H_    256
#define NE_   34
#define NA_   36
#define M_    8192      // L_*B_
#define KP_   304       // D_ padded to multiple of 16
#define NPROJ_ 2048     // 2 dirs * 4H
#define K2_   512       // 2H
#define NCAT_ 128       // 36 (part_j) + 36 (part_i) + 34 (logit_h) padded to 128

#define JREG_ 24        // W_hh kp-chunks held in registers (per gate)
#define JLDS_ 8         // W_hh kp-chunks held in LDS (32 - JREG_)

__device__ __forceinline__ float sigmoidf_(float x) { return 1.0f / (1.0f + expf(-x)); }

typedef __attribute__((ext_vector_type(2))) _Float16 half2_;

__device__ __forceinline__ half2_ u2h(unsigned u) {
    union { unsigned u; half2_ h; } c; c.u = u; return c.h;
}
__device__ __forceinline__ unsigned packh2(float a, float b) {
    union { half2_ h; unsigned u; } c;
    c.h = half2_{(_Float16)a, (_Float16)b};
    return c.u;
}

#if __has_builtin(__builtin_amdgcn_fdot2)
__device__ __forceinline__ float fdot2_(half2_ a, half2_ b, float c) {
    return __builtin_amdgcn_fdot2(a, b, c, false);
}
#else
__device__ __forceinline__ float fdot2_(half2_ a, half2_ b, float c) {
    return c + (float)a.x * (float)b.x + (float)a.y * (float)b.y;
}
#endif

// ---------------------------------------------------------------------------
// K1: gather embeddings into X (M_ x KP_), zero-padded K tail. X[m][k], m = l*B_+b
__global__ __launch_bounds__(256) void k_gather(const float* __restrict__ emb,
                                                const int* __restrict__ ids,
                                                float* __restrict__ X) {
    int idx = blockIdx.x * 256 + threadIdx.x;
    if (idx >= M_ * KP_) return;
    int m = idx / KP_, k = idx - m * KP_;
    int l = m >> 6, b = m & 63;
    float v = 0.f;
    if (k < D_) {
        int tok = ids[b * L_ + l];
        v = emb[(size_t)tok * D_ + k];
    }
    X[idx] = v;
}

// K2: transposed input-proj weights Wt_ih (KP_ x NPROJ_) + combined bias
__global__ __launch_bounds__(256) void k_prep_wih(const float* __restrict__ Wf,
                                                  const float* __restrict__ Wb,
                                                  const float* __restrict__ bihf,
                                                  const float* __restrict__ bhhf,
                                                  const float* __restrict__ bihb,
                                                  const float* __restrict__ bhhb,
                                                  float* __restrict__ Wt,
                                                  float* __restrict__ bias) {
    int idx = blockIdx.x * 256 + threadIdx.x;
    if (idx >= KP_ * NPROJ_) return;
    int k = idx / NPROJ_, n = idx - k * NPROJ_;
    int dir = n >> 10, g = n & 1023;
    float v = 0.f;
    if (k < D_) v = dir ? Wb[g * D_ + k] : Wf[g * D_ + k];
    Wt[idx] = v;
    if (k == 0) bias[n] = dir ? (bihb[g] + bhhb[g]) : (bihf[g] + bhhf[g]);
}

// K3: pack W_hh to fp16 half2 in register-load order:
//   uint4 element Wr4[(dir*32 + j)*1024 + g] = { w2(g, 4j+0..3) }
//   where w2(g, kp) = packh2(W[g][2kp], W[g][2kp+1]).
// Lane g reads chunk j at stride 16 B -> perfectly coalesced.
__global__ __launch_bounds__(256) void k_prep_whh16(const float* __restrict__ Wf,
                                                    const float* __restrict__ Wb,
                                                    unsigned* __restrict__ Wp) {
    int idx = blockIdx.x * 256 + threadIdx.x;       // 2*128*1024 uints
    if (idx >= 2 * 128 * 1024) return;
    int dir = idx >> 17, r = idx & 131071;
    int j = r >> 12;                                 // kp-chunk 0..31
    int g = (r >> 2) & 1023;                         // gate
    int c = r & 3;
    int kp = (j << 2) | c;
    const float* W = dir ? Wb : Wf;
    Wp[idx] = packh2(W[g * H_ + 2 * kp], W[g * H_ + 2 * kp + 1]);
}

// K4: combined head weights Wcat (K2_ x NCAT_)
__global__ __launch_bounds__(256) void k_prep_wcat(const float* __restrict__ Warg,
                                                   const float* __restrict__ Wev,
                                                   const float* __restrict__ barg,
                                                   const float* __restrict__ bev,
                                                   float* __restrict__ Wcat,
                                                   float* __restrict__ bias) {
    int idx = blockIdx.x * 256 + threadIdx.x;
    if (idx >= K2_ * NCAT_) return;
    int k = idx >> 7, n = idx & 127;
    float v = 0.f;
    if (n < 36)       v = Warg[n * 1024 + k];
    else if (n < 72)  v = Warg[(n - 36) * 1024 + 512 + k];
    else if (n < 106) v = Wev[(n - 72) * 545 + k];
    Wcat[idx] = v;
    if (k == 0) {
        float bv = 0.f;
        if (n >= 36 && n < 72)       bv = barg[n - 36];
        else if (n >= 72 && n < 106) bv = bev[n - 72];
        bias[n] = bv;
    }
}

// ---------------------------------------------------------------------------
// Generic fp32 tiled GEMM: C (MxN) = A (MxK) * Bm (KxN) + bias[n]
template <int K>
__global__ __launch_bounds__(256) void k_gemm(const float* __restrict__ A,
                                              const float* __restrict__ Bm,
                                              const float* __restrict__ bias,
                                              float* __restrict__ C, int N) {
    __shared__ float As[16][64];
    __shared__ float Bs[16][64];
    const int tid = threadIdx.x;
    const int m0 = blockIdx.x * 64, n0 = blockIdx.y * 64;
    const int tx = tid & 15, ty = tid >> 4;
    const int a_m = tid >> 2;
    const int a_k = (tid & 3) << 2;
    const int b_k = tid >> 4;
    const int b_n = (tid & 15) << 2;

    float acc[4][4] = {};
    for (int k0 = 0; k0 < K; k0 += 16) {
        float4 av = *(const float4*)&A[(size_t)(m0 + a_m) * K + k0 + a_k];
        float4 bv = *(const float4*)&Bm[(size_t)(k0 + b_k) * N + n0 + b_n];
        __syncthreads();
        As[a_k][a_m] = av.x; As[a_k + 1][a_m] = av.y;
        As[a_k + 2][a_m] = av.z; As[a_k + 3][a_m] = av.w;
        *(float4*)&Bs[b_k][b_n] = bv;
        __syncthreads();
#pragma unroll
        for (int kk = 0; kk < 16; kk++) {
            float4 a4 = *(const float4*)&As[kk][ty << 2];
            float4 b4 = *(const float4*)&Bs[kk][tx << 2];
            float ar[4] = {a4.x, a4.y, a4.z, a4.w};
            float br[4] = {b4.x, b4.y, b4.z, b4.w};
#pragma unroll
            for (int i = 0; i < 4; i++)
#pragma unroll
                for (int j = 0; j < 4; j++) acc[i][j] += ar[i] * br[j];
        }
    }
    float4 bb = *(const float4*)&bias[n0 + (tx << 2)];
#pragma unroll
    for (int i = 0; i < 4; i++) {
        int m = m0 + (ty << 2) + i;
        float4 o;
        o.x = acc[i][0] + bb.x; o.y = acc[i][1] + bb.y;
        o.z = acc[i][2] + bb.z; o.w = acc[i][3] + bb.w;
        *(float4*)&C[(size_t)m * N + n0 + (tx << 2)] = o;
    }
}

// ---------------------------------------------------------------------------
// BiLSTM v7: true W-residency. v6's lesson (VGPR_Count=64): at 1024 threads
// the 128-VGPR cap forced the compiler to sink W loads into the step loop,
// re-streaming 512 KB/step from L2 (3.85 us/step = the per-CU L2-fill floor).
// Now: 512 threads (8 waves = 2/SIMD -> 256-VGPR cap), each thread owns
// 2 gates (g, g+512). W split: chunks 0..23 in registers (2*24*4 = 192 VGPR),
// chunks 24..31 in LDS (128 KB, dynamic). Per step: zero global W traffic;
// 256 fdot2/thread against wave-uniform h2s broadcasts; 2 local barriers.
__global__ __launch_bounds__(512, 2) void k_lstm7(const float* __restrict__ pre,
                                                  const unsigned* __restrict__ Wp,
                                                  float* __restrict__ hs) {
    extern __shared__ __align__(16) char smem7[];
    uint4*    WL4  = (uint4*)smem7;                        // [JLDS_][1024]      = 131072 B
    float*    pbuf = (float*)(smem7 + 131072);             // [1024]             =   4096 B
    unsigned* h2s  = (unsigned*)(smem7 + 131072 + 4096);   // [128]              =    512 B

    const int blk = blockIdx.x;                 // dir*64 + b
    const int dir = blk >> 6;
    const int b   = blk & 63;
    const int tid = threadIdx.x;                // 0..511
    const int g0  = tid;
    const int g1  = tid + 512;

    const uint4* Wr4 = (const uint4*)Wp + ((size_t)dir << 15);   // dir * 32*1024

    // ---- prologue: LDS chunks JREG_..31 (coalesced), reg chunks 0..JREG_-1 ----
    for (int it = 0; it < 16; ++it) {
        int i2 = tid + (it << 9);               // 0..8191 uint4s
        int j  = i2 >> 10;                      // 0..7
        int g  = i2 & 1023;
        WL4[(j << 10) + g] = Wr4[(size_t)(JREG_ + j) * 1024 + g];
    }
    uint4 w0[JREG_], w1[JREG_];
#pragma unroll
    for (int j = 0; j < JREG_; ++j) {
        w0[j] = Wr4[(size_t)j * 1024 + g0];
        w1[j] = Wr4[(size_t)j * 1024 + g1];
    }
    if (tid < 128) h2s[tid] = 0u;
    __syncthreads();

    const uint4* h2s4 = (const uint4*)h2s;
    float c_state = 0.f;                        // live for tid < 256 (unit u = tid)

    for (int step = 0; step < L_; ++step) {
        const int l = dir ? (L_ - 1 - step) : step;
        const float* p = pre + ((size_t)(l * B_ + b) << 11) + (dir << 10);
        float acc0 = p[g0];
        float acc1 = p[g1];

#pragma unroll
        for (int j = 0; j < JREG_; ++j) {
            uint4 h4 = h2s4[j];                 // wave-uniform broadcast read
            acc0 = fdot2_(u2h(w0[j].x), u2h(h4.x), acc0);
            acc0 = fdot2_(u2h(w0[j].y), u2h(h4.y), acc0);
            acc0 = fdot2_(u2h(w0[j].z), u2h(h4.z), acc0);
            acc0 = fdot2_(u2h(w0[j].w), u2h(h4.w), acc0);
            acc1 = fdot2_(u2h(w1[j].x), u2h(h4.x), acc1);
            acc1 = fdot2_(u2h(w1[j].y), u2h(h4.y), acc1);
            acc1 = fdot2_(u2h(w1[j].z), u2h(h4.z), acc1);
            acc1 = fdot2_(u2h(w1[j].w), u2h(h4.w), acc1);
        }
#pragma unroll
        for (int j = 0; j < JLDS_; ++j) {
            uint4 h4 = h2s4[JREG_ + j];
            uint4 wa = WL4[(j << 10) + g0];     // contiguous across lanes: conflict-free
            uint4 wb = WL4[(j << 10) + g1];
            acc0 = fdot2_(u2h(wa.x), u2h(h4.x), acc0);
            acc0 = fdot2_(u2h(wa.y), u2h(h4.y), acc0);
            acc0 = fdot2_(u2h(wa.z), u2h(h4.z), acc0);
            acc0 = fdot2_(u2h(wa.w), u2h(h4.w), acc0);
            acc1 = fdot2_(u2h(wb.x), u2h(h4.x), acc1);
            acc1 = fdot2_(u2h(wb.y), u2h(h4.y), acc1);
            acc1 = fdot2_(u2h(wb.z), u2h(h4.z), acc1);
            acc1 = fdot2_(u2h(wb.w), u2h(h4.w), acc1);
        }
        pbuf[g0] = acc0;
        pbuf[g1] = acc1;
        __syncthreads();                        // B1: gates ready

        // ---- cell update: threads 0..255 (unit u) ----
        if (tid < 256) {
            const int u = tid;
            float ig = sigmoidf_(pbuf[u]);
            float fg = sigmoidf_(pbuf[256 + u]);
            float gg = tanhf(pbuf[512 + u]);
            float og = sigmoidf_(pbuf[768 + u]);
            float c = fg * c_state + ig * gg;
            c_state = c;
            float h = og * tanhf(c);
            hs[((size_t)(l * B_ + b) << 9) + (dir << 8) + u] = h;
            float hn = __shfl_xor(h, 1, 64);    // partner u^1, same wave
            if (!(u & 1)) h2s[u >> 1] = packh2(h, hn);
        }
        __syncthreads();                        // B2: h2s ready for next step
    }
}

// ---------------------------------------------------------------------------
// Event head sequential scan. One block (1 wave) per batch row.
__global__ __launch_bounds__(64) void k_event(const float* __restrict__ part,
                                              const float* __restrict__ Wev,
                                              float* __restrict__ out_ev) {
    const int b = blockIdx.x;
    const int e = threadIdx.x;
    __shared__ float sg[33];
    if (e < 33) sg[e] = 0.f;
    float wreg[33];
    if (e < NE_) {
#pragma unroll
        for (int j = 0; j < 33; j++) wreg[j] = Wev[e * 545 + 512 + j];
    }
    __syncthreads();
    for (int l = 0; l < L_; l++) {
        const int m = l * B_ + b;
        float v = -3.0e38f;
        if (e < NE_) {
            v = part[(size_t)m * NCAT_ + 72 + e];
#pragma unroll
            for (int j = 0; j < 33; j++) v += wreg[j] * sg[j];
            out_ev[((size_t)b * L_ + l) * NE_ + e] = v;
        }
        float bv = v;
        int bi = e;
#pragma unroll
        for (int off = 32; off > 0; off >>= 1) {
            float ov = __shfl_xor(bv, off, 64);
            int oi = __shfl_xor(bi, off, 64);
            if (ov > bv || (ov == bv && oi < bi)) { bv = ov; bi = oi; }
        }
        __syncthreads();
        if (bi > 0 && e == bi - 1) sg[e] = 1.f;
        __syncthreads();
    }
}

// ---------------------------------------------------------------------------
// Argument logits broadcast: out[b][i][j][a] = part_i[b][i][a] + part_j[b][j][a]
__global__ __launch_bounds__(256) void k_arg(const float* __restrict__ part,
                                             float* __restrict__ out) {
    const int blk = blockIdx.x;            // b*L_ + i
    const int b = blk >> 7, i = blk & 127;
    __shared__ float pj[L_ * NA_];
    __shared__ float pi_s[NA_];
    const int tid = threadIdx.x;
    if (tid < NA_) pi_s[tid] = part[(size_t)(i * B_ + b) * NCAT_ + 36 + tid];
    for (int idx = tid; idx < L_ * NA_; idx += 256) {
        int j = idx / NA_, a = idx - j * NA_;
        pj[idx] = part[(size_t)(j * B_ + b) * NCAT_ + a];
    }
    __syncthreads();
    float* o = out + (size_t)blk * (L_ * NA_);
    for (int idx = tid; idx < L_ * NA_; idx += 256) {
        int a = idx % NA_;
        o[idx] = pi_s[a] + pj[idx];
    }
}

// ---------------------------------------------------------------------------
extern "C" void kernel_launch(void* const* d_in, const int* in_sizes, int n_in,
                              void* d_out, int out_size, void* d_ws, size_t ws_size,
                              hipStream_t stream) {
    const float* emb  = (const float*)d_in[0];
    const float* Wihf = (const float*)d_in[1];
    const float* Whhf = (const float*)d_in[2];
    const float* bihf = (const float*)d_in[3];
    const float* bhhf = (const float*)d_in[4];
    const float* Wihb = (const float*)d_in[5];
    const float* Whhb = (const float*)d_in[6];
    const float* bihb = (const float*)d_in[7];
    const float* bhhb = (const float*)d_in[8];
    const float* Wev  = (const float*)d_in[9];
    const float* bev  = (const float*)d_in[10];
    const float* Warg = (const float*)d_in[11];
    const float* barg = (const float*)d_in[12];
    const int*   ids  = (const int*)d_in[13];
    float* out = (float*)d_out;
    float* ws  = (float*)d_ws;

    // Workspace layout (floats). X region reused for `part` (post-lstm only).
    float*    X       = ws;                 // 8192*304  (dead after gemm1)
    float*    part    = ws;                 // 8192*128 (written by gemm2, after lstm)
    float*    Wt_ih   = ws + 2490368;       // 304*2048
    float*    bias_p  = ws + 3112960;       // 2048
    unsigned* Wp16    = (unsigned*)(ws + 3115008);  // 2*128*1024 uints (262144)
    float*    Wcat    = ws + 3639296;       // 512*128
    float*    bias_c  = ws + 3704832;       // 128
    float*    pre_all = ws + 3704960;       // 8192*2048
    float*    hsbuf   = ws + 20482176;      // 8192*512

    static bool s_attr_done = false;
    if (!s_attr_done) {
        (void)hipFuncSetAttribute(reinterpret_cast<const void*>(k_lstm7),
                                  hipFuncAttributeMaxDynamicSharedMemorySize, 135680);
        s_attr_done = true;
    }

    k_gather<<<(M_ * KP_) / 256, 256, 0, stream>>>(emb, ids, X);
    k_prep_wih<<<(KP_ * NPROJ_) / 256, 256, 0, stream>>>(Wihf, Wihb, bihf, bhhf, bihb, bhhb, Wt_ih, bias_p);
    k_prep_whh16<<<(2 * 128 * 1024) / 256, 256, 0, stream>>>(Whhf, Whhb, Wp16);
    k_prep_wcat<<<(K2_ * NCAT_) / 256, 256, 0, stream>>>(Warg, Wev, barg, bev, Wcat, bias_c);

    k_gemm<KP_><<<dim3(M_ / 64, NPROJ_ / 64), 256, 0, stream>>>(X, Wt_ih, bias_p, pre_all, NPROJ_);
    k_lstm7<<<128, 512, 135680, stream>>>(pre_all, Wp16, hsbuf);
    k_gemm<K2_><<<dim3(M_ / 64, NCAT_ / 64), 256, 0, stream>>>(hsbuf, Wcat, bias_c, part, NCAT_);
    k_event<<<B_, 64, 0, stream>>>(part, Wev, out);
    k_arg<<<B_ * L_, 256, 0, stream>>>(part, out + (size_t)B_ * L_ * NE_);
}

// Round 7
// 792.405 us; speedup vs baseline: 2.0811x; 1.0050x over previous
//
#include <hip/hip_runtime.h>
#include <cstddef>
#include <cmath>

// Problem constants
#define B_    64
#define L_    128
#define V_    20000
#define D_    300
#define H_    256
#define NE_   34
#define NA_   36
#define M_    8192      // L_*B_
#define KP_   304       // D_ padded to multiple of 16
#define NPROJ_ 2048     // 2 dirs * 4H
#define K2_   512       // 2H
#define NCAT_ 128       // 36 (part_j) + 36 (part_i) + 34 (logit_h) padded to 128

#define JREG_ 24        // W_hh kp-chunks held in registers (per gate)
#define JLDS_ 8         // W_hh kp-chunks held in LDS (32 - JREG_)

__device__ __forceinline__ float sigmoidf_(float x) { return 1.0f / (1.0f + expf(-x)); }

typedef __attribute__((ext_vector_type(2))) _Float16 half2_;

__device__ __forceinline__ half2_ u2h(unsigned u) {
    union { unsigned u; half2_ h; } c; c.u = u; return c.h;
}
__device__ __forceinline__ unsigned packh2(float a, float b) {
    union { half2_ h; unsigned u; } c;
    c.h = half2_{(_Float16)a, (_Float16)b};
    return c.u;
}

#if __has_builtin(__builtin_amdgcn_fdot2)
__device__ __forceinline__ float fdot2_(half2_ a, half2_ b, float c) {
    return __builtin_amdgcn_fdot2(a, b, c, false);
}
#else
__device__ __forceinline__ float fdot2_(half2_ a, half2_ b, float c) {
    return c + (float)a.x * (float)b.x + (float)a.y * (float)b.y;
}
#endif

// ---------------------------------------------------------------------------
// K1: gather embeddings into X (M_ x KP_), zero-padded K tail. X[m][k], m = l*B_+b
__global__ __launch_bounds__(256) void k_gather(const float* __restrict__ emb,
                                                const int* __restrict__ ids,
                                                float* __restrict__ X) {
    int idx = blockIdx.x * 256 + threadIdx.x;
    if (idx >= M_ * KP_) return;
    int m = idx / KP_, k = idx - m * KP_;
    int l = m >> 6, b = m & 63;
    float v = 0.f;
    if (k < D_) {
        int tok = ids[b * L_ + l];
        v = emb[(size_t)tok * D_ + k];
    }
    X[idx] = v;
}

// K2: transposed input-proj weights Wt_ih (KP_ x NPROJ_) + combined bias
__global__ __launch_bounds__(256) void k_prep_wih(const float* __restrict__ Wf,
                                                  const float* __restrict__ Wb,
                                                  const float* __restrict__ bihf,
                                                  const float* __restrict__ bhhf,
                                                  const float* __restrict__ bihb,
                                                  const float* __restrict__ bhhb,
                                                  float* __restrict__ Wt,
                                                  float* __restrict__ bias) {
    int idx = blockIdx.x * 256 + threadIdx.x;
    if (idx >= KP_ * NPROJ_) return;
    int k = idx / NPROJ_, n = idx - k * NPROJ_;
    int dir = n >> 10, g = n & 1023;
    float v = 0.f;
    if (k < D_) v = dir ? Wb[g * D_ + k] : Wf[g * D_ + k];
    Wt[idx] = v;
    if (k == 0) bias[n] = dir ? (bihb[g] + bhhb[g]) : (bihf[g] + bhhf[g]);
}

// K3: pack W_hh to fp16 half2 in register-load order:
//   uint4 element Wr4[(dir*32 + j)*1024 + g] = { w2(g, 4j+0..3) }
//   where w2(g, kp) = packh2(W[g][2kp], W[g][2kp+1]).
// Lane g reads chunk j at stride 16 B -> perfectly coalesced.
__global__ __launch_bounds__(256) void k_prep_whh16(const float* __restrict__ Wf,
                                                    const float* __restrict__ Wb,
                                                    unsigned* __restrict__ Wp) {
    int idx = blockIdx.x * 256 + threadIdx.x;       // 2*128*1024 uints
    if (idx >= 2 * 128 * 1024) return;
    int dir = idx >> 17, r = idx & 131071;
    int j = r >> 12;                                 // kp-chunk 0..31
    int g = (r >> 2) & 1023;                         // gate
    int c = r & 3;
    int kp = (j << 2) | c;
    const float* W = dir ? Wb : Wf;
    Wp[idx] = packh2(W[g * H_ + 2 * kp], W[g * H_ + 2 * kp + 1]);
}

// K4: combined head weights Wcat (K2_ x NCAT_)
__global__ __launch_bounds__(256) void k_prep_wcat(const float* __restrict__ Warg,
                                                   const float* __restrict__ Wev,
                                                   const float* __restrict__ barg,
                                                   const float* __restrict__ bev,
                                                   float* __restrict__ Wcat,
                                                   float* __restrict__ bias) {
    int idx = blockIdx.x * 256 + threadIdx.x;
    if (idx >= K2_ * NCAT_) return;
    int k = idx >> 7, n = idx & 127;
    float v = 0.f;
    if (n < 36)       v = Warg[n * 1024 + k];
    else if (n < 72)  v = Warg[(n - 36) * 1024 + 512 + k];
    else if (n < 106) v = Wev[(n - 72) * 545 + k];
    Wcat[idx] = v;
    if (k == 0) {
        float bv = 0.f;
        if (n >= 36 && n < 72)       bv = barg[n - 36];
        else if (n >= 72 && n < 106) bv = bev[n - 72];
        bias[n] = bv;
    }
}

// ---------------------------------------------------------------------------
// Generic fp32 tiled GEMM: C (MxN) = A (MxK) * Bm (KxN) + bias[n]
template <int K>
__global__ __launch_bounds__(256) void k_gemm(const float* __restrict__ A,
                                              const float* __restrict__ Bm,
                                              const float* __restrict__ bias,
                                              float* __restrict__ C, int N) {
    __shared__ float As[16][64];
    __shared__ float Bs[16][64];
    const int tid = threadIdx.x;
    const int m0 = blockIdx.x * 64, n0 = blockIdx.y * 64;
    const int tx = tid & 15, ty = tid >> 4;
    const int a_m = tid >> 2;
    const int a_k = (tid & 3) << 2;
    const int b_k = tid >> 4;
    const int b_n = (tid & 15) << 2;

    float acc[4][4] = {};
    for (int k0 = 0; k0 < K; k0 += 16) {
        float4 av = *(const float4*)&A[(size_t)(m0 + a_m) * K + k0 + a_k];
        float4 bv = *(const float4*)&Bm[(size_t)(k0 + b_k) * N + n0 + b_n];
        __syncthreads();
        As[a_k][a_m] = av.x; As[a_k + 1][a_m] = av.y;
        As[a_k + 2][a_m] = av.z; As[a_k + 3][a_m] = av.w;
        *(float4*)&Bs[b_k][b_n] = bv;
        __syncthreads();
#pragma unroll
        for (int kk = 0; kk < 16; kk++) {
            float4 a4 = *(const float4*)&As[kk][ty << 2];
            float4 b4 = *(const float4*)&Bs[kk][tx << 2];
            float ar[4] = {a4.x, a4.y, a4.z, a4.w};
            float br[4] = {b4.x, b4.y, b4.z, b4.w};
#pragma unroll
            for (int i = 0; i < 4; i++)
#pragma unroll
                for (int j = 0; j < 4; j++) acc[i][j] += ar[i] * br[j];
        }
    }
    float4 bb = *(const float4*)&bias[n0 + (tx << 2)];
#pragma unroll
    for (int i = 0; i < 4; i++) {
        int m = m0 + (ty << 2) + i;
        float4 o;
        o.x = acc[i][0] + bb.x; o.y = acc[i][1] + bb.y;
        o.z = acc[i][2] + bb.z; o.w = acc[i][3] + bb.w;
        *(float4*)&C[(size_t)m * N + n0 + (tx << 2)] = o;
    }
}

// ---------------------------------------------------------------------------
// BiLSTM v8b: v7 + forced W residency (compile-fixed: pin 32-bit components,
// not uint4 aggregates — "+v" on a 128-bit struct is a tied INDIRECT operand
// the backend rejects).
//   v7's counters (VGPR_Count=128, 2.56 us/step = 384 KB / 64 B/cyc L2 fill)
//   proved the compiler sank ALL w0/w1 loads into the step loop: dynamic LDS
//   is invisible at compile time, so LLVM chose the 128-VGPR / 4-waves-per-EU
//   occupancy bucket it can never get at runtime (135 KB LDS -> 1 block/CU).
//   Fixes: (a) amdgpu_waves_per_eu(2,2) pins the budget at 256 VGPRs;
//   (b) per-component asm "+v" pins after the prologue loads make sinking
//   illegal; (c) acc starts at 0 and `pre` is added at the end, so the
//   per-step global load latency overlaps the whole dot loop.
__global__ __launch_bounds__(512)
__attribute__((amdgpu_waves_per_eu(2, 2)))
void k_lstm8(const float* __restrict__ pre,
             const unsigned* __restrict__ Wp,
             float* __restrict__ hs) {
    extern __shared__ __align__(16) char smem7[];
    uint4*    WL4  = (uint4*)smem7;                        // [JLDS_][1024]      = 131072 B
    float*    pbuf = (float*)(smem7 + 131072);             // [1024]             =   4096 B
    unsigned* h2s  = (unsigned*)(smem7 + 131072 + 4096);   // [128]              =    512 B

    const int blk = blockIdx.x;                 // dir*64 + b
    const int dir = blk >> 6;
    const int b   = blk & 63;
    const int tid = threadIdx.x;                // 0..511
    const int g0  = tid;
    const int g1  = tid + 512;

    const uint4* Wr4 = (const uint4*)Wp + ((size_t)dir << 15);   // dir * 32*1024

    // ---- prologue: LDS chunks JREG_..31 (coalesced), reg chunks 0..JREG_-1 ----
    for (int it = 0; it < 16; ++it) {
        int i2 = tid + (it << 9);               // 0..8191 uint4s
        int j  = i2 >> 10;                      // 0..7
        int g  = i2 & 1023;
        WL4[(j << 10) + g] = Wr4[(size_t)(JREG_ + j) * 1024 + g];
    }
    uint4 w0[JREG_], w1[JREG_];
#pragma unroll
    for (int j = 0; j < JREG_; ++j) {
        w0[j] = Wr4[(size_t)j * 1024 + g0];
        w1[j] = Wr4[(size_t)j * 1024 + g1];
    }
    // Pin W in registers: the asm pretends to modify each 32-bit component,
    // so the loads cannot be rematerialized/sunk into the step loop.
#pragma unroll
    for (int j = 0; j < JREG_; ++j) {
        asm volatile("" : "+v"(w0[j].x), "+v"(w0[j].y), "+v"(w0[j].z), "+v"(w0[j].w),
                          "+v"(w1[j].x), "+v"(w1[j].y), "+v"(w1[j].z), "+v"(w1[j].w));
    }
    if (tid < 128) h2s[tid] = 0u;
    __syncthreads();

    const uint4* h2s4 = (const uint4*)h2s;
    float c_state = 0.f;                        // live for tid < 256 (unit u = tid)

    for (int step = 0; step < L_; ++step) {
        const int l = dir ? (L_ - 1 - step) : step;
        const float* p = pre + ((size_t)(l * B_ + b) << 11) + (dir << 10);
        float pv0 = p[g0];                      // issue early; consumed at the end
        float pv1 = p[g1];
        float acc0 = 0.f;
        float acc1 = 0.f;

#pragma unroll
        for (int j = 0; j < JREG_; ++j) {
            uint4 h4 = h2s4[j];                 // wave-uniform broadcast read
            acc0 = fdot2_(u2h(w0[j].x), u2h(h4.x), acc0);
            acc0 = fdot2_(u2h(w0[j].y), u2h(h4.y), acc0);
            acc0 = fdot2_(u2h(w0[j].z), u2h(h4.z), acc0);
            acc0 = fdot2_(u2h(w0[j].w), u2h(h4.w), acc0);
            acc1 = fdot2_(u2h(w1[j].x), u2h(h4.x), acc1);
            acc1 = fdot2_(u2h(w1[j].y), u2h(h4.y), acc1);
            acc1 = fdot2_(u2h(w1[j].z), u2h(h4.z), acc1);
            acc1 = fdot2_(u2h(w1[j].w), u2h(h4.w), acc1);
        }
#pragma unroll
        for (int j = 0; j < JLDS_; ++j) {
            uint4 h4 = h2s4[JREG_ + j];
            uint4 wa = WL4[(j << 10) + g0];     // contiguous across lanes: conflict-free
            uint4 wb = WL4[(j << 10) + g1];
            acc0 = fdot2_(u2h(wa.x), u2h(h4.x), acc0);
            acc0 = fdot2_(u2h(wa.y), u2h(h4.y), acc0);
            acc0 = fdot2_(u2h(wa.z), u2h(h4.z), acc0);
            acc0 = fdot2_(u2h(wa.w), u2h(h4.w), acc0);
            acc1 = fdot2_(u2h(wb.x), u2h(h4.x), acc1);
            acc1 = fdot2_(u2h(wb.y), u2h(h4.y), acc1);
            acc1 = fdot2_(u2h(wb.z), u2h(h4.z), acc1);
            acc1 = fdot2_(u2h(wb.w), u2h(h4.w), acc1);
        }
        pbuf[g0] = acc0 + pv0;
        pbuf[g1] = acc1 + pv1;
        __syncthreads();                        // B1: gates ready

        // ---- cell update: threads 0..255 (unit u) ----
        if (tid < 256) {
            const int u = tid;
            float ig = sigmoidf_(pbuf[u]);
            float fg = sigmoidf_(pbuf[256 + u]);
            float gg = tanhf(pbuf[512 + u]);
            float og = sigmoidf_(pbuf[768 + u]);
            float c = fg * c_state + ig * gg;
            c_state = c;
            float h = og * tanhf(c);
            hs[((size_t)(l * B_ + b) << 9) + (dir << 8) + u] = h;
            float hn = __shfl_xor(h, 1, 64);    // partner u^1, same wave
            if (!(u & 1)) h2s[u >> 1] = packh2(h, hn);
        }
        __syncthreads();                        // B2: h2s ready for next step
    }
}

// ---------------------------------------------------------------------------
// Event head sequential scan. One block (1 wave) per batch row.
__global__ __launch_bounds__(64) void k_event(const float* __restrict__ part,
                                              const float* __restrict__ Wev,
                                              float* __restrict__ out_ev) {
    const int b = blockIdx.x;
    const int e = threadIdx.x;
    __shared__ float sg[33];
    if (e < 33) sg[e] = 0.f;
    float wreg[33];
    if (e < NE_) {
#pragma unroll
        for (int j = 0; j < 33; j++) wreg[j] = Wev[e * 545 + 512 + j];
    }
    __syncthreads();
    for (int l = 0; l < L_; l++) {
        const int m = l * B_ + b;
        float v = -3.0e38f;
        if (e < NE_) {
            v = part[(size_t)m * NCAT_ + 72 + e];
#pragma unroll
            for (int j = 0; j < 33; j++) v += wreg[j] * sg[j];
            out_ev[((size_t)b * L_ + l) * NE_ + e] = v;
        }
        float bv = v;
        int bi = e;
#pragma unroll
        for (int off = 32; off > 0; off >>= 1) {
            float ov = __shfl_xor(bv, off, 64);
            int oi = __shfl_xor(bi, off, 64);
            if (ov > bv || (ov == bv && oi < bi)) { bv = ov; bi = oi; }
        }
        __syncthreads();
        if (bi > 0 && e == bi - 1) sg[e] = 1.f;
        __syncthreads();
    }
}

// ---------------------------------------------------------------------------
// Argument logits broadcast: out[b][i][j][a] = part_i[b][i][a] + part_j[b][j][a]
__global__ __launch_bounds__(256) void k_arg(const float* __restrict__ part,
                                             float* __restrict__ out) {
    const int blk = blockIdx.x;            // b*L_ + i
    const int b = blk >> 7, i = blk & 127;
    __shared__ float pj[L_ * NA_];
    __shared__ float pi_s[NA_];
    const int tid = threadIdx.x;
    if (tid < NA_) pi_s[tid] = part[(size_t)(i * B_ + b) * NCAT_ + 36 + tid];
    for (int idx = tid; idx < L_ * NA_; idx += 256) {
        int j = idx / NA_, a = idx - j * NA_;
        pj[idx] = part[(size_t)(j * B_ + b) * NCAT_ + a];
    }
    __syncthreads();
    float* o = out + (size_t)blk * (L_ * NA_);
    for (int idx = tid; idx < L_ * NA_; idx += 256) {
        int a = idx % NA_;
        o[idx] = pi_s[a] + pj[idx];
    }
}

// ---------------------------------------------------------------------------
extern "C" void kernel_launch(void* const* d_in, const int* in_sizes, int n_in,
                              void* d_out, int out_size, void* d_ws, size_t ws_size,
                              hipStream_t stream) {
    const float* emb  = (const float*)d_in[0];
    const float* Wihf = (const float*)d_in[1];
    const float* Whhf = (const float*)d_in[2];
    const float* bihf = (const float*)d_in[3];
    const float* bhhf = (const float*)d_in[4];
    const float* Wihb = (const float*)d_in[5];
    const float* Whhb = (const float*)d_in[6];
    const float* bihb = (const float*)d_in[7];
    const float* bhhb = (const float*)d_in[8];
    const float* Wev  = (const float*)d_in[9];
    const float* bev  = (const float*)d_in[10];
    const float* Warg = (const float*)d_in[11];
    const float* barg = (const float*)d_in[12];
    const int*   ids  = (const int*)d_in[13];
    float* out = (float*)d_out;
    float* ws  = (float*)d_ws;

    // Workspace layout (floats). X region reused for `part` (post-lstm only).
    float*    X       = ws;                 // 8192*304  (dead after gemm1)
    float*    part    = ws;                 // 8192*128 (written by gemm2, after lstm)
    float*    Wt_ih   = ws + 2490368;       // 304*2048
    float*    bias_p  = ws + 3112960;       // 2048
    unsigned* Wp16    = (unsigned*)(ws + 3115008);  // 2*128*1024 uints (262144)
    float*    Wcat    = ws + 3639296;       // 512*128
    float*    bias_c  = ws + 3704832;       // 128
    float*    pre_all = ws + 3704960;       // 8192*2048
    float*    hsbuf   = ws + 20482176;      // 8192*512

    static bool s_attr_done = false;
    if (!s_attr_done) {
        (void)hipFuncSetAttribute(reinterpret_cast<const void*>(k_lstm8),
                                  hipFuncAttributeMaxDynamicSharedMemorySize, 135680);
        s_attr_done = true;
    }

    k_gather<<<(M_ * KP_) / 256, 256, 0, stream>>>(emb, ids, X);
    k_prep_wih<<<(KP_ * NPROJ_) / 256, 256, 0, stream>>>(Wihf, Wihb, bihf, bhhf, bihb, bhhb, Wt_ih, bias_p);
    k_prep_whh16<<<(2 * 128 * 1024) / 256, 256, 0, stream>>>(Whhf, Whhb, Wp16);
    k_prep_wcat<<<(K2_ * NCAT_) / 256, 256, 0, stream>>>(Warg, Wev, barg, bev, Wcat, bias_c);

    k_gemm<KP_><<<dim3(M_ / 64, NPROJ_ / 64), 256, 0, stream>>>(X, Wt_ih, bias_p, pre_all, NPROJ_);
    k_lstm8<<<128, 512, 135680, stream>>>(pre_all, Wp16, hsbuf);
    k_gemm<K2_><<<dim3(M_ / 64, NCAT_ / 64), 256, 0, stream>>>(hsbuf, Wcat, bias_c, part, NCAT_);
    k_event<<<B_, 64, 0, stream>>>(part, Wev, out);
    k_arg<<<B_ * L_, 256, 0, stream>>>(part, out + (size_t)B_ * L_ * NE_);
}